// Round 3
// baseline (797.850 us; speedup 1.0000x reference)
//
#include <hip/hip_runtime.h>
#include <hip/hip_bf16.h>

#define NE 8
#define DIN 1024
#define DHID 4096
#define DOUTD 1024
#define NTOK 32768
#define CAP (NTOK / NE)  // 4096 tokens per expert

typedef unsigned short u16;
typedef __attribute__((ext_vector_type(8))) short bf16x8;   // 8 bf16 = 4 VGPR
typedef __attribute__((ext_vector_type(4))) float f32x4;

__device__ __forceinline__ u16 f2bf(float x) {
  unsigned u = __builtin_bit_cast(unsigned, x);
  u += 0x7fffu + ((u >> 16) & 1u);   // RNE; inputs are finite normals
  return (u16)(u >> 16);
}

__device__ __forceinline__ float gelu_erf(float x) {
  return 0.5f * x * (1.0f + erff(x * 0.70710678118654752f));
}

__device__ __forceinline__ void async_ld16(const void* g, void* l) {
  __builtin_amdgcn_global_load_lds(
      (const __attribute__((address_space(1))) unsigned int*)g,
      (__attribute__((address_space(3))) unsigned int*)l, 16, 0, 0);
}

// ---------------- fp32 -> bf16, 8 elems/thread ----------------
__global__ __launch_bounds__(256) void convert_bf16_kernel(const float* __restrict__ in,
                                                           u16* __restrict__ out) {
  size_t i = ((size_t)blockIdx.x * 256 + threadIdx.x) * 8;
  float4 a = *(const float4*)(in + i);
  float4 b = *(const float4*)(in + i + 4);
  uint4 o;
  o.x = (unsigned)f2bf(a.x) | ((unsigned)f2bf(a.y) << 16);
  o.y = (unsigned)f2bf(a.z) | ((unsigned)f2bf(a.w) << 16);
  o.z = (unsigned)f2bf(b.x) | ((unsigned)f2bf(b.y) << 16);
  o.w = (unsigned)f2bf(b.z) | ((unsigned)f2bf(b.w) << 16);
  *(uint4*)(out + i) = o;
}

// ------------- [E][K][N] fp32 -> [E][N][K] bf16 (64x64 LDS-tiled) -------------
__global__ __launch_bounds__(256) void transpose_bf16_kernel(const float* __restrict__ in,
                                                             u16* __restrict__ out,
                                                             int K, int N) {
  __shared__ __align__(16) u16 tile[64 * 72];
  const int e = blockIdx.z;
  const int n0 = blockIdx.x * 64;
  const int k0 = blockIdx.y * 64;
  const float* inp = in + (size_t)e * K * N;
  u16* outp = out + (size_t)e * N * K;
  const int t = threadIdx.x;
  const int kr = t >> 4;
  const int nc = (t & 15) * 4;
#pragma unroll
  for (int rr = 0; rr < 4; ++rr) {
    int kl = rr * 16 + kr;
    float4 v = *(const float4*)(inp + (size_t)(k0 + kl) * N + n0 + nc);
    tile[(nc + 0) * 72 + kl] = f2bf(v.x);
    tile[(nc + 1) * 72 + kl] = f2bf(v.y);
    tile[(nc + 2) * 72 + kl] = f2bf(v.z);
    tile[(nc + 3) * 72 + kl] = f2bf(v.w);
  }
  __syncthreads();
  const int nr = t >> 3;
  const int kc = (t & 7) * 8;
#pragma unroll
  for (int it = 0; it < 2; ++it) {
    int nl = it * 32 + nr;
    bf16x8 w = *(const bf16x8*)(tile + nl * 72 + kc);
    *(bf16x8*)(outp + (size_t)(n0 + nl) * K + k0 + kc) = w;
  }
}

// ---------------------------- grouped GEMM, 256x256 tile, phase-split ----------------------------
// C[e] = A[e] (CAP x K bf16 row-major) @ Bt[e]^T (Bt: N x K bf16 row-major).
// 8 waves (2M x 4N), per-wave output 128x64 (acc[8][4] of f32x4).
// BK=32, ring-3 LDS (3 x 32KiB: A 16K + B 16K per buffer). Per K-tile: 2 phases
// (ms=0 rows, ms=1 rows), each phase:
//   {2x global_load_lds (stage 8KB unit of tile t+2) | 8-or-4 ds_read_b128 |
//    s_barrier | lgkmcnt(0)+sched_barrier(0) | setprio(1) 16 MFMA setprio(0) | s_barrier}
// vmcnt ledger (per thread, 2 loads/phase, 4/tile, stage t+2 during t):
//   tile-end wait vmcnt(3): carried 3 + issued 4 -> retires ALL of tile t+1
//   (+unit0 of t+2). Tail: vmcnt(0) at NT-2; none at NT-1. Never 0 in steady state.
// LDS layout per 256x32 tile: [128 lds-rows][8 x 16B units]; global (r,k):
//   lds_row=r&127, logical unit lu=(r>>7)*4+(k>>3), phys ucol=lu^(lds_row&7)  (T2).
// Staged via linear LDS dest + inverse-swizzled global source (rule #21).
template <int K, int N, bool GELU_OUT>
__global__ __launch_bounds__(512, 2) void moe_gemm256_kernel(
    const u16* __restrict__ A, const u16* __restrict__ Bt,
    const float* __restrict__ bias, void* __restrict__ Out) {
  extern __shared__ __align__(16) char sm[];
  constexpr int TX = N / 256;
  constexpr int NT = K / 32;

  const int bid = blockIdx.x;
  const int e = bid & 7;          // XCD swizzle: nwg%8==0, one expert per XCD
  const int idx = bid >> 3;
  const int m0 = (idx / TX) * 256;
  const int n0 = (idx % TX) * 256;

  const u16* Ae = A + (size_t)e * CAP * K;
  const u16* Be = Bt + (size_t)e * N * K;

  const int tid = threadIdx.x;
  const int l = tid & 63;
  const int w = tid >> 6;
  const int wr = w >> 2;          // 0..1 (M)
  const int wc = w & 3;           // 0..3 (N)
  const int g = l >> 4;           // 0..3
  const int rl = l & 15;

  // ---- ds_read byte offsets (swizzled), within buffer ----
  int aoff0[4], aoff1[4], boff[4];
#pragma unroll
  for (int q = 0; q < 4; ++q) {
    aoff0[q] = (q * 16 + rl) * 128 + ((((wr << 2) + g) ^ (rl & 7)) << 4);
    aoff1[q] = aoff0[q] + 64 * 128;
  }
#pragma unroll
  for (int i = 0; i < 4; ++i) {
    int row = wc * 64 + i * 16 + rl;
    boff[i] = 16384 + (row & 127) * 128 + (((((row >> 7) << 2) + g) ^ (rl & 7)) << 4);
  }

  // ---- staging source offsets (inverse-swizzled global) ----
  // slot idx within region: lds_row=idx>>3, ucol=idx&7, lu=ucol^(lds_row&7),
  // r=lds_row+128*(lu>=4), ku=lu&3 -> elem off (base0+r)*K + ku*8
  auto mkoff = [&](int sidx, int base0) -> size_t {
    int lrow = sidx >> 3, ucol = sidx & 7;
    int lu = ucol ^ (lrow & 7);
    int r = lrow + ((lu & 4) << 5);
    return (size_t)(base0 + r) * K + (lu & 3) * 8;
  };
  const size_t sA0 = mkoff(tid, m0), sA1 = mkoff(512 + tid, m0);
  const size_t sB0 = mkoff(tid, n0), sB1 = mkoff(512 + tid, n0);
  const int dA0 = tid * 16, dA1 = 8192 + tid * 16;
  const int dB0 = 16384 + tid * 16, dB1 = 24576 + tid * 16;

  f32x4 acc[8][4] = {};

  // prologue: stage tile 0 -> buf0, tile 1 -> buf1; wait tile0 (4 outstanding ok)
  async_ld16(Ae + sA0, sm + dA0);
  async_ld16(Ae + sA1, sm + dA1);
  async_ld16(Be + sB0, sm + dB0);
  async_ld16(Be + sB1, sm + dB1);
  async_ld16(Ae + sA0 + 32, sm + 32768 + dA0);
  async_ld16(Ae + sA1 + 32, sm + 32768 + dA1);
  async_ld16(Be + sB0 + 32, sm + 32768 + dB0);
  async_ld16(Be + sB1 + 32, sm + 32768 + dB1);
  asm volatile("s_waitcnt vmcnt(4)\n\ts_barrier" ::: "memory");

  int b0 = 0, b1 = 32768, b2 = 65536;   // read | next | stage-target (t+2)

#pragma unroll 1
  for (int tt = 0; tt < NT; ++tt) {
    const bool st = (tt + 2 < NT);
    const size_t kb2 = (size_t)(tt + 2) * 32;
    bf16x8 afr[4], bfr[4];
    // ================= phase 0 (ms=0) =================
    if (st) {
      async_ld16(Ae + sA0 + kb2, sm + b2 + dA0);
      async_ld16(Ae + sA1 + kb2, sm + b2 + dA1);
    }
#pragma unroll
    for (int i = 0; i < 4; ++i) bfr[i] = *(const bf16x8*)(sm + b0 + boff[i]);
#pragma unroll
    for (int q = 0; q < 4; ++q) afr[q] = *(const bf16x8*)(sm + b0 + aoff0[q]);
    __builtin_amdgcn_s_barrier();
    asm volatile("s_waitcnt lgkmcnt(0)" ::: "memory");
    __builtin_amdgcn_sched_barrier(0);
    __builtin_amdgcn_s_setprio(1);
#pragma unroll
    for (int q = 0; q < 4; ++q)
#pragma unroll
      for (int i = 0; i < 4; ++i)
        acc[q][i] = __builtin_amdgcn_mfma_f32_16x16x32_bf16(bfr[i], afr[q], acc[q][i], 0, 0, 0);
    __builtin_amdgcn_s_setprio(0);
    __builtin_amdgcn_s_barrier();
    // ================= phase 1 (ms=1) =================
    if (st) {
      async_ld16(Be + sB0 + kb2, sm + b2 + dB0);
      async_ld16(Be + sB1 + kb2, sm + b2 + dB1);
    }
#pragma unroll
    for (int q = 0; q < 4; ++q) afr[q] = *(const bf16x8*)(sm + b0 + aoff1[q]);
    __builtin_amdgcn_s_barrier();
    asm volatile("s_waitcnt lgkmcnt(0)" ::: "memory");
    __builtin_amdgcn_sched_barrier(0);
    __builtin_amdgcn_s_setprio(1);
#pragma unroll
    for (int q = 0; q < 4; ++q)
#pragma unroll
      for (int i = 0; i < 4; ++i)
        acc[4 + q][i] = __builtin_amdgcn_mfma_f32_16x16x32_bf16(bfr[i], afr[q], acc[4 + q][i], 0, 0, 0);
    __builtin_amdgcn_s_setprio(0);
    if (tt < NT - 2) {
      asm volatile("s_waitcnt vmcnt(3)\n\ts_barrier" ::: "memory");
    } else if (tt == NT - 2) {
      asm volatile("s_waitcnt vmcnt(0)\n\ts_barrier" ::: "memory");
    }
    // rotate ring
    int tmp = b0; b0 = b1; b1 = b2; b2 = tmp;
  }

  // epilogue
  const float* be = bias + (size_t)e * N;
  const int mb = m0 + wr * 128 + rl;
  const int nb = n0 + wc * 64 + g * 4;
  if constexpr (GELU_OUT) {
    u16* Oe = (u16*)Out + (size_t)e * (size_t)CAP * N;
#pragma unroll
    for (int j = 0; j < 8; ++j) {
      int m = mb + j * 16;
#pragma unroll
      for (int i = 0; i < 4; ++i) {
        int n = nb + i * 16;
        float4 bv = *(const float4*)(be + n);
        ushort4 o;
        o.x = f2bf(gelu_erf(acc[j][i][0] + bv.x));
        o.y = f2bf(gelu_erf(acc[j][i][1] + bv.y));
        o.z = f2bf(gelu_erf(acc[j][i][2] + bv.z));
        o.w = f2bf(gelu_erf(acc[j][i][3] + bv.w));
        *(ushort4*)(Oe + (size_t)m * N + n) = o;
      }
    }
  } else {
    float* Oe = (float*)Out + (size_t)e * (size_t)CAP * N;
#pragma unroll
    for (int j = 0; j < 8; ++j) {
      int m = mb + j * 16;
#pragma unroll
      for (int i = 0; i < 4; ++i) {
        int n = nb + i * 16;
        float4 bv = *(const float4*)(be + n);
        float4 o;
        o.x = acc[j][i][0] + bv.x;
        o.y = acc[j][i][1] + bv.y;
        o.z = acc[j][i][2] + bv.z;
        o.w = acc[j][i][3] + bv.w;
        *(float4*)(Oe + (size_t)m * N + n) = o;
      }
    }
  }
}

extern "C" void kernel_launch(void* const* d_in, const int* in_sizes, int n_in,
                              void* d_out, int out_size, void* d_ws, size_t ws_size,
                              hipStream_t stream) {
  const float* x  = (const float*)d_in[0];
  // d_in[1] = expert_size (equal splits by construction; unused)
  const float* w1 = (const float*)d_in[2];
  const float* b1 = (const float*)d_in[3];
  const float* w2 = (const float*)d_in[4];
  const float* b2 = (const float*)d_in[5];
  float* out = (float*)d_out;

  char* wsp = (char*)d_ws;
  u16* x_bf = (u16*)(wsp);                             // 64 MiB
  u16* w1t  = (u16*)(wsp + (size_t)67108864);          // 64 MiB  [E][DHID][DIN]
  u16* w2t  = (u16*)(wsp + (size_t)134217728);         // 64 MiB  [E][DOUT][DHID]
  u16* h    = (u16*)(wsp + (size_t)201326592);         // 256 MiB [NTOK][DHID]

  hipFuncSetAttribute(reinterpret_cast<const void*>(moe_gemm256_kernel<DIN, DHID, true>),
                      hipFuncAttributeMaxDynamicSharedMemorySize, 98304);
  hipFuncSetAttribute(reinterpret_cast<const void*>(moe_gemm256_kernel<DHID, DOUTD, false>),
                      hipFuncAttributeMaxDynamicSharedMemorySize, 98304);

  convert_bf16_kernel<<<(NTOK * DIN) / (256 * 8), 256, 0, stream>>>(x, x_bf);
  transpose_bf16_kernel<<<dim3(DHID / 64, DIN / 64, NE), 256, 0, stream>>>(w1, w1t, DIN, DHID);
  transpose_bf16_kernel<<<dim3(DOUTD / 64, DHID / 64, NE), 256, 0, stream>>>(w2, w2t, DHID, DOUTD);

  moe_gemm256_kernel<DIN, DHID, true>
      <<<dim3(NE * (CAP / 256) * (DHID / 256)), 512, 98304, stream>>>(x_bf, w1t, b1, h);
  moe_gemm256_kernel<DHID, DOUTD, false>
      <<<dim3(NE * (CAP / 256) * (DOUTD / 256)), 512, 98304, stream>>>(h, w2t, b2, out);
}

// Round 4
// 789.808 us; speedup vs baseline: 1.0102x; 1.0102x over previous
//
#include <hip/hip_runtime.h>
#include <hip/hip_bf16.h>
#include <type_traits>

#define NE 8
#define DIN 1024
#define DHID 4096
#define DOUTD 1024
#define NTOK 32768
#define CAP (NTOK / NE)  // 4096 tokens per expert

typedef unsigned short u16;
typedef __attribute__((ext_vector_type(8))) short bf16x8;    // 8 bf16 = 4 VGPR
typedef __attribute__((ext_vector_type(16))) float f32x16;   // 32x32 MFMA acc

template <int I> using ic = std::integral_constant<int, I>;

__device__ __forceinline__ u16 f2bf(float x) {
  unsigned u = __builtin_bit_cast(unsigned, x);
  u += 0x7fffu + ((u >> 16) & 1u);   // RNE; finite normals
  return (u16)(u >> 16);
}

// tanh-form GELU (max dev from erf-form ~3e-4; threshold headroom 4.6x)
__device__ __forceinline__ float gelu_f(float x) {
  float u = 0.7978845608028654f * x * (1.0f + 0.044715f * x * x);
  float t = __expf(-2.0f * fabsf(u));
  float r = __fdividef(2.0f * t, 1.0f + t);   // 1 - tanh|u|
  float th = copysignf(1.0f - r, u);
  return 0.5f * x * (1.0f + th);
}

__device__ __forceinline__ void async_ld16(const void* g, void* l) {
  __builtin_amdgcn_global_load_lds(
      (const __attribute__((address_space(1))) unsigned int*)g,
      (__attribute__((address_space(3))) unsigned int*)l, 16, 0, 0);
}

// ---------------- fp32 -> bf16, 8 elems/thread ----------------
__global__ __launch_bounds__(256) void convert_bf16_kernel(const float* __restrict__ in,
                                                           u16* __restrict__ out) {
  size_t i = ((size_t)blockIdx.x * 256 + threadIdx.x) * 8;
  float4 a = *(const float4*)(in + i);
  float4 b = *(const float4*)(in + i + 4);
  uint4 o;
  o.x = (unsigned)f2bf(a.x) | ((unsigned)f2bf(a.y) << 16);
  o.y = (unsigned)f2bf(a.z) | ((unsigned)f2bf(a.w) << 16);
  o.z = (unsigned)f2bf(b.x) | ((unsigned)f2bf(b.y) << 16);
  o.w = (unsigned)f2bf(b.z) | ((unsigned)f2bf(b.w) << 16);
  *(uint4*)(out + i) = o;
}

// ------------- [E][K][N] fp32 -> [E][N][K] bf16 (64x64 LDS-tiled) -------------
__global__ __launch_bounds__(256) void transpose_bf16_kernel(const float* __restrict__ in,
                                                             u16* __restrict__ out,
                                                             int K, int N) {
  __shared__ __align__(16) u16 tile[64 * 72];
  const int e = blockIdx.z;
  const int n0 = blockIdx.x * 64;
  const int k0 = blockIdx.y * 64;
  const float* inp = in + (size_t)e * K * N;
  u16* outp = out + (size_t)e * N * K;
  const int t = threadIdx.x;
  const int kr = t >> 4;
  const int nc = (t & 15) * 4;
#pragma unroll
  for (int rr = 0; rr < 4; ++rr) {
    int kl = rr * 16 + kr;
    float4 v = *(const float4*)(inp + (size_t)(k0 + kl) * N + n0 + nc);
    tile[(nc + 0) * 72 + kl] = f2bf(v.x);
    tile[(nc + 1) * 72 + kl] = f2bf(v.y);
    tile[(nc + 2) * 72 + kl] = f2bf(v.z);
    tile[(nc + 3) * 72 + kl] = f2bf(v.w);
  }
  __syncthreads();
  const int nr = t >> 3;
  const int kc = (t & 7) * 8;
#pragma unroll
  for (int it = 0; it < 2; ++it) {
    int nl = it * 32 + nr;
    bf16x8 w = *(const bf16x8*)(tile + nl * 72 + kc);
    *(bf16x8*)(outp + (size_t)(n0 + nl) * K + k0 + kc) = w;
  }
}

// ---------------------------- grouped GEMM, 256x256, ring-4, static offsets ----------------------------
// C[e] = A[e] (CAP x K bf16 row-major) @ Bt[e]^T (Bt: N x K bf16 row-major).
// 8 waves (2M x 4N), per-wave output 128x64, MFMA 32x32x16 (acc f32x16[4][2]).
// BK=32, ring-4 LDS (4 x 32KiB = 128 KiB), K-loop unrolled by 4 so ALL LDS
// addresses are base + constexpr immediate (zero per-tile VALU addressing).
// Prefetch depth 3: tile t stages t+3 (ring[(t+3)&3] consumed at t-1 -> safe).
// vmcnt ledger (per thread, 4 loads/tile): steady end-of-tile wait vmcnt(8)
// leaves t+2,t+3 in flight; tail 8,4,0,none. Never drains in steady state (T4).
// Per tile 2 phases: {stage 2 | ds_read 8-or-4 | s_barrier | lgkmcnt(0) |
// setprio(1) 8xMFMA setprio(0) | barrier-or-fused-vmcnt-barrier} (T3).
// LDS tile layout (proven R1-R3, 0 conflicts): region [128 rows][8 x 16B units];
// global (r,k): lds_row=r&127, lu=(r>>7)*4+(k>>3), phys unit=lu^(lds_row&7) (T2);
// staged via linear LDS dest + inverse-swizzled global source (rule #21).
// MFMA operands swapped (Aop=weights, Bop=tokens); C/D per m74/m101:
//   token row = lane&31 (+mf*32+wr*128), col = (r&3)+8*(r>>2)+4*(lane>>5) (+nf*32+wc*64)
template <int K, int N, bool GELU_OUT>
__global__ __launch_bounds__(512, 2) void moe_gemm256_kernel(
    const u16* __restrict__ A, const u16* __restrict__ Bt,
    const float* __restrict__ bias, void* __restrict__ Out) {
  extern __shared__ __align__(16) char smem_raw[];
  constexpr int TX = N / 256;
  constexpr int NT = K / 32;
  static_assert(NT % 4 == 0 && NT >= 8, "K-tile count");

  const int bid = blockIdx.x;
  const int e = bid & 7;          // XCD swizzle: nwg%8==0, one expert per XCD
  const int idx = bid >> 3;
  const int m0 = (idx / TX) * 256;
  const int n0 = (idx % TX) * 256;

  const u16* Ae = A + (size_t)e * CAP * K;
  const u16* Be = Bt + (size_t)e * N * K;

  const int tid = threadIdx.x;
  const int l = tid & 63;
  const int w = tid >> 6;
  const int wr = w >> 2;          // 0..1 (M)
  const int wc = w & 3;           // 0..3 (N)
  const int l31 = l & 31;
  const int lhi = l >> 5;         // 0..1

  const char* smL = smem_raw;
  const char* smH = smem_raw + 65536;

  // ---- ds_read byte offsets within a buffer (swizzled, loop-invariant) ----
  int taoff[4][2], wboff[2][2];
#pragma unroll
  for (int mf = 0; mf < 4; ++mf)
#pragma unroll
    for (int kh = 0; kh < 2; ++kh) {
      int r = wr * 128 + mf * 32 + l31;
      int ku = kh * 2 + lhi;
      int r7 = r & 127;
      int lu = (r >> 7) * 4 + ku;
      taoff[mf][kh] = r7 * 128 + ((lu ^ (r7 & 7)) << 4);
    }
#pragma unroll
  for (int nf = 0; nf < 2; ++nf)
#pragma unroll
    for (int kh = 0; kh < 2; ++kh) {
      int r = wc * 64 + nf * 32 + l31;
      int ku = kh * 2 + lhi;
      int r7 = r & 127;
      int lu = (r >> 7) * 4 + ku;
      wboff[nf][kh] = 16384 + r7 * 128 + ((lu ^ (r7 & 7)) << 4);
    }

  // ---- staging: linear LDS dest + inverse-swizzled global source (rule #21) ----
  auto mkoff = [&](int sidx, int base0) -> size_t {
    int lrow = sidx >> 3, pu = sidx & 7;
    int lu = pu ^ (lrow & 7);
    int r = lrow + ((lu & 4) << 5);
    return (size_t)(base0 + r) * K + (lu & 3) * 8;
  };
  const u16* gA0 = Ae + mkoff(tid, m0);
  const u16* gA1 = Ae + mkoff(512 + tid, m0);
  const u16* gB0 = Be + mkoff(tid, n0);
  const u16* gB1 = Be + mkoff(512 + tid, n0);
  const int dA0 = tid * 16, dA1 = 8192 + tid * 16;
  const int dB0 = 16384 + tid * 16, dB1 = 24576 + tid * 16;

  f32x16 acc[4][2] = {};

  // ---- prologue: stage tiles 0,1,2 into bufs 0,1,2 ----
  auto prost = [&](auto SBC, int kb) {
    constexpr int SB = decltype(SBC)::value;
    char* sd = (char*)(((SB >= 2) ? smH : smL) + (SB & 1) * 32768);
    async_ld16((const char*)gA0 + kb, sd + dA0);
    async_ld16((const char*)gA1 + kb, sd + dA1);
    async_ld16((const char*)gB0 + kb, sd + dB0);
    async_ld16((const char*)gB1 + kb, sd + dB1);
  };
  prost(ic<0>{}, 0);
  prost(ic<1>{}, 64);
  prost(ic<2>{}, 128);
  asm volatile("s_waitcnt vmcnt(8)\n\ts_barrier" ::: "memory");

  // ---- one K-tile: buf J (constexpr), optional stage of J+3, end-wait WN ----
  auto tileb = [&](auto JC, auto STC, auto WNC) {
    constexpr int J = decltype(JC)::value;
    constexpr bool ST = decltype(STC)::value;
    constexpr int WN = decltype(WNC)::value;
    constexpr int SB = (J + 3) & 3;
    constexpr int KOFF = (J + 3) * 64;   // bytes from current group base
    const char* sr = ((J >= 2) ? smH : smL) + (J & 1) * 32768;
    char* sd = (char*)(((SB >= 2) ? smH : smL) + (SB & 1) * 32768);
    bf16x8 wf[2][2], t01[2][2], t23[2][2];
    // ================= phase 0 (mf 0,1) =================
    if constexpr (ST) {
      async_ld16((const char*)gA0 + KOFF, sd + dA0);
      async_ld16((const char*)gA1 + KOFF, sd + dA1);
    }
#pragma unroll
    for (int nf = 0; nf < 2; ++nf)
#pragma unroll
      for (int kh = 0; kh < 2; ++kh) wf[nf][kh] = *(const bf16x8*)(sr + wboff[nf][kh]);
#pragma unroll
    for (int mf = 0; mf < 2; ++mf)
#pragma unroll
      for (int kh = 0; kh < 2; ++kh) t01[mf][kh] = *(const bf16x8*)(sr + taoff[mf][kh]);
    __builtin_amdgcn_s_barrier();
    asm volatile("s_waitcnt lgkmcnt(0)");
    __builtin_amdgcn_s_setprio(1);
#pragma unroll
    for (int kh = 0; kh < 2; ++kh)
#pragma unroll
      for (int mf = 0; mf < 2; ++mf)
#pragma unroll
        for (int nf = 0; nf < 2; ++nf)
          acc[mf][nf] = __builtin_amdgcn_mfma_f32_32x32x16_bf16(
              wf[nf][kh], t01[mf][kh], acc[mf][nf], 0, 0, 0);
    __builtin_amdgcn_s_setprio(0);
    __builtin_amdgcn_s_barrier();
    // ================= phase 1 (mf 2,3) =================
    if constexpr (ST) {
      async_ld16((const char*)gB0 + KOFF, sd + dB0);
      async_ld16((const char*)gB1 + KOFF, sd + dB1);
    }
#pragma unroll
    for (int mf = 0; mf < 2; ++mf)
#pragma unroll
      for (int kh = 0; kh < 2; ++kh) t23[mf][kh] = *(const bf16x8*)(sr + taoff[2 + mf][kh]);
    __builtin_amdgcn_s_barrier();
    asm volatile("s_waitcnt lgkmcnt(0)");
    __builtin_amdgcn_s_setprio(1);
#pragma unroll
    for (int kh = 0; kh < 2; ++kh)
#pragma unroll
      for (int mf = 0; mf < 2; ++mf)
#pragma unroll
        for (int nf = 0; nf < 2; ++nf)
          acc[2 + mf][nf] = __builtin_amdgcn_mfma_f32_32x32x16_bf16(
              wf[nf][kh], t23[mf][kh], acc[2 + mf][nf], 0, 0, 0);
    __builtin_amdgcn_s_setprio(0);
    if constexpr (WN >= 0) {
      asm volatile("s_waitcnt vmcnt(%0)\n\ts_barrier" :: "n"(WN) : "memory");
    }
  };

  // ---- main: groups of 4 tiles, all steady-state (stage, vmcnt(8)) ----
#pragma unroll 1
  for (int g = 0; g < (NT - 4) / 4; ++g) {
    tileb(ic<0>{}, std::true_type{}, ic<8>{});
    tileb(ic<1>{}, std::true_type{}, ic<8>{});
    tileb(ic<2>{}, std::true_type{}, ic<8>{});
    tileb(ic<3>{}, std::true_type{}, ic<8>{});
    gA0 += 128; gA1 += 128; gB0 += 128; gB1 += 128;   // 4 tiles * 32 elems
  }
  // ---- final group: tiles NT-4..NT-1 ----
  tileb(ic<0>{}, std::true_type{}, ic<8>{});    // stages NT-1
  tileb(ic<1>{}, std::false_type{}, ic<4>{});
  tileb(ic<2>{}, std::false_type{}, ic<0>{});
  tileb(ic<3>{}, std::false_type{}, ic<-1>{});

  // ---- epilogue ----
  const float* be = bias + (size_t)e * N;
  const int mrow = m0 + wr * 128 + l31;
  const int ncb = n0 + wc * 64 + lhi * 4;
  if constexpr (GELU_OUT) {
    u16* Oe = (u16*)Out + (size_t)e * (size_t)CAP * N;
#pragma unroll
    for (int mf = 0; mf < 4; ++mf) {
      int m = mrow + mf * 32;
#pragma unroll
      for (int nf = 0; nf < 2; ++nf)
#pragma unroll
        for (int q = 0; q < 4; ++q) {
          int n = ncb + nf * 32 + q * 8;
          float4 bv = *(const float4*)(be + n);
          ushort4 o;
          o.x = f2bf(gelu_f(acc[mf][nf][4 * q + 0] + bv.x));
          o.y = f2bf(gelu_f(acc[mf][nf][4 * q + 1] + bv.y));
          o.z = f2bf(gelu_f(acc[mf][nf][4 * q + 2] + bv.z));
          o.w = f2bf(gelu_f(acc[mf][nf][4 * q + 3] + bv.w));
          *(ushort4*)(Oe + (size_t)m * N + n) = o;
        }
    }
  } else {
    float* Oe = (float*)Out + (size_t)e * (size_t)CAP * N;
#pragma unroll
    for (int mf = 0; mf < 4; ++mf) {
      int m = mrow + mf * 32;
#pragma unroll
      for (int nf = 0; nf < 2; ++nf)
#pragma unroll
        for (int q = 0; q < 4; ++q) {
          int n = ncb + nf * 32 + q * 8;
          float4 bv = *(const float4*)(be + n);
          float4 o;
          o.x = acc[mf][nf][4 * q + 0] + bv.x;
          o.y = acc[mf][nf][4 * q + 1] + bv.y;
          o.z = acc[mf][nf][4 * q + 2] + bv.z;
          o.w = acc[mf][nf][4 * q + 3] + bv.w;
          *(float4*)(Oe + (size_t)m * N + n) = o;
        }
    }
  }
}

extern "C" void kernel_launch(void* const* d_in, const int* in_sizes, int n_in,
                              void* d_out, int out_size, void* d_ws, size_t ws_size,
                              hipStream_t stream) {
  const float* x  = (const float*)d_in[0];
  // d_in[1] = expert_size (equal splits by construction; unused)
  const float* w1 = (const float*)d_in[2];
  const float* b1 = (const float*)d_in[3];
  const float* w2 = (const float*)d_in[4];
  const float* b2 = (const float*)d_in[5];
  float* out = (float*)d_out;

  char* wsp = (char*)d_ws;
  u16* x_bf = (u16*)(wsp);                             // 64 MiB
  u16* w1t  = (u16*)(wsp + (size_t)67108864);          // 64 MiB  [E][DHID][DIN]
  u16* w2t  = (u16*)(wsp + (size_t)134217728);         // 64 MiB  [E][DOUT][DHID]
  u16* h    = (u16*)(wsp + (size_t)201326592);         // 256 MiB [NTOK][DHID]

  hipFuncSetAttribute(reinterpret_cast<const void*>(moe_gemm256_kernel<DIN, DHID, true>),
                      hipFuncAttributeMaxDynamicSharedMemorySize, 131072);
  hipFuncSetAttribute(reinterpret_cast<const void*>(moe_gemm256_kernel<DHID, DOUTD, false>),
                      hipFuncAttributeMaxDynamicSharedMemorySize, 131072);

  convert_bf16_kernel<<<(NTOK * DIN) / (256 * 8), 256, 0, stream>>>(x, x_bf);
  transpose_bf16_kernel<<<dim3(DHID / 64, DIN / 64, NE), 256, 0, stream>>>(w1, w1t, DIN, DHID);
  transpose_bf16_kernel<<<dim3(DOUTD / 64, DHID / 64, NE), 256, 0, stream>>>(w2, w2t, DHID, DOUTD);

  moe_gemm256_kernel<DIN, DHID, true>
      <<<dim3(NE * (CAP / 256) * (DHID / 256)), 512, 131072, stream>>>(x_bf, w1t, b1, h);
  moe_gemm256_kernel<DHID, DOUTD, false>
      <<<dim3(NE * (CAP / 256) * (DOUTD / 256)), 512, 131072, stream>>>(h, w2t, b2, out);
}

// Round 5
// 739.136 us; speedup vs baseline: 1.0794x; 1.0686x over previous
//
#include <hip/hip_runtime.h>
#include <hip/hip_bf16.h>
#include <type_traits>

#define NE 8
#define DIN 1024
#define DHID 4096
#define DOUTD 1024
#define NTOK 32768
#define CAP (NTOK / NE)  // 4096 tokens per expert

typedef unsigned short u16;
typedef __attribute__((ext_vector_type(8))) short bf16x8;   // 8 bf16 = 4 VGPR
typedef __attribute__((ext_vector_type(4))) float f32x4;

template <int I> using ic = std::integral_constant<int, I>;

__device__ __forceinline__ u16 f2bf(float x) {
  unsigned u = __builtin_bit_cast(unsigned, x);
  u += 0x7fffu + ((u >> 16) & 1u);   // RNE; finite normals
  return (u16)(u >> 16);
}

// tanh-form GELU (max dev from erf-form ~3e-4; threshold headroom ~4.6x; R4-verified)
__device__ __forceinline__ float gelu_f(float x) {
  float u = 0.7978845608028654f * x * (1.0f + 0.044715f * x * x);
  float t = __expf(-2.0f * fabsf(u));
  float r = __fdividef(2.0f * t, 1.0f + t);   // 1 - tanh|u|
  float th = copysignf(1.0f - r, u);
  return 0.5f * x * (1.0f + th);
}

__device__ __forceinline__ void async_ld16(const void* g, void* l) {
  __builtin_amdgcn_global_load_lds(
      (const __attribute__((address_space(1))) unsigned int*)g,
      (__attribute__((address_space(3))) unsigned int*)l, 16, 0, 0);
}

// ---------------- fp32 -> bf16, 8 elems/thread ----------------
__global__ __launch_bounds__(256) void convert_bf16_kernel(const float* __restrict__ in,
                                                           u16* __restrict__ out) {
  size_t i = ((size_t)blockIdx.x * 256 + threadIdx.x) * 8;
  float4 a = *(const float4*)(in + i);
  float4 b = *(const float4*)(in + i + 4);
  uint4 o;
  o.x = (unsigned)f2bf(a.x) | ((unsigned)f2bf(a.y) << 16);
  o.y = (unsigned)f2bf(a.z) | ((unsigned)f2bf(a.w) << 16);
  o.z = (unsigned)f2bf(b.x) | ((unsigned)f2bf(b.y) << 16);
  o.w = (unsigned)f2bf(b.z) | ((unsigned)f2bf(b.w) << 16);
  *(uint4*)(out + i) = o;
}

// ------------- [E][K][N] fp32 -> [E][N][K] bf16 (64x64 LDS-tiled) -------------
__global__ __launch_bounds__(256) void transpose_bf16_kernel(const float* __restrict__ in,
                                                             u16* __restrict__ out,
                                                             int K, int N) {
  __shared__ __align__(16) u16 tile[64 * 72];
  const int e = blockIdx.z;
  const int n0 = blockIdx.x * 64;
  const int k0 = blockIdx.y * 64;
  const float* inp = in + (size_t)e * K * N;
  u16* outp = out + (size_t)e * N * K;
  const int t = threadIdx.x;
  const int kr = t >> 4;
  const int nc = (t & 15) * 4;
#pragma unroll
  for (int rr = 0; rr < 4; ++rr) {
    int kl = rr * 16 + kr;
    float4 v = *(const float4*)(inp + (size_t)(k0 + kl) * N + n0 + nc);
    tile[(nc + 0) * 72 + kl] = f2bf(v.x);
    tile[(nc + 1) * 72 + kl] = f2bf(v.y);
    tile[(nc + 2) * 72 + kl] = f2bf(v.z);
    tile[(nc + 3) * 72 + kl] = f2bf(v.w);
  }
  __syncthreads();
  const int nr = t >> 3;
  const int kc = (t & 7) * 8;
#pragma unroll
  for (int it = 0; it < 2; ++it) {
    int nl = it * 32 + nr;
    bf16x8 w = *(const bf16x8*)(tile + nl * 72 + kc);
    *(bf16x8*)(outp + (size_t)(n0 + nl) * K + k0 + kc) = w;
  }
}

// -------------- grouped GEMM, 256x256, ring-4, 1 barrier/tile, counted lgkmcnt --------------
// C[e] = A[e] (CAP x K bf16 row-major) @ Bt[e]^T (Bt: N x K bf16 row-major).
// 8 waves (2M x 4N), per-wave 128x64, MFMA 16x16x32 (acc f32x4[8][4]).
// BK=32, ring-4 LDS (4 x 32KiB = 128 KiB), K-loop unrolled by 4 => all LDS addrs
// are base + constexpr immediate (R4's VALU fix). Prefetch depth 3 (stage t+3 at t).
// Per tile: {4x global_load_lds | 12x ds_read_b128 (bfr[4],afr[8]) |
//   lgkmcnt(4)+SBAR0 | setprio(1) 16 MFMA | lgkmcnt(0)+SBAR0 | 16 MFMA setprio(0) |
//   fused vmcnt(WN)+s_barrier}. ONE barrier/tile (R4 had 4); counted lgkmcnt hides
// afr[4..7] latency under the first MFMA cluster (rule #18 sched_barrier after waits).
// vmcnt ledger (4 loads/tile/thread): end-of-t outstanding = t+1,t+2,t+3 = 12;
// wait vmcnt(8) retires t+1 (needed next). Tail: 8,4,0,none. Never drains (T4).
// Race-freedom with 1 barrier/tile: all ds_reads of buf[t] retire at t's lgkmcnt(0)
// (pre-barrier); buf[(t+3)&3]=buf[(t-1)&3] was fully read during t-1, behind the
// end-of-(t-1) barrier; its staging issues after that barrier. Safe.
// LDS tile layout (R1-R3, measured 0 conflicts): region [128 lds-rows][8 x 16B units];
// global (r,k): lds_row=r&127, lu=(r>>7)*4+(k>>3), phys unit=lu^(lds_row&7) (T2);
// staged via linear LDS dest + inverse-swizzled global source (rule #21).
// 16x16 frag reads (lanes 0-7 hit 8 distinct units -> conflict-free, unlike R4's 32x32).
// MFMA swapped (Aop=weights bfr, Bop=tokens afr); C/D per R3 (verified):
//   acc[j][i] lane l reg r -> C[m0+wr*128+j*16+(l&15)][n0+wc*64+i*16+(l>>4)*4+r]
template <int K, int N, bool GELU_OUT>
__global__ __launch_bounds__(512, 2) void moe_gemm256_kernel(
    const u16* __restrict__ A, const u16* __restrict__ Bt,
    const float* __restrict__ bias, void* __restrict__ Out) {
  extern __shared__ __align__(16) char smem_raw[];
  constexpr int TX = N / 256;
  constexpr int NT = K / 32;
  static_assert(NT % 4 == 0 && NT >= 8, "K-tile count");

  const int bid = blockIdx.x;
  const int e = bid & 7;          // XCD swizzle: nwg%8==0, one expert per XCD
  const int idx = bid >> 3;
  const int m0 = (idx / TX) * 256;
  const int n0 = (idx % TX) * 256;

  const u16* Ae = A + (size_t)e * CAP * K;
  const u16* Be = Bt + (size_t)e * N * K;

  const int tid = threadIdx.x;
  const int l = tid & 63;
  const int w = tid >> 6;
  const int wr = w >> 2;          // 0..1 (M)
  const int wc = w & 3;           // 0..3 (N)
  const int g = l >> 4;           // 0..3 (k-unit)
  const int rl = l & 15;

  const char* smL = smem_raw;
  const char* smH = smem_raw + 65536;

  // ---- ds_read byte offsets within a buffer (swizzled, loop-invariant) ----
  int aoff[8], boff[4];
#pragma unroll
  for (int j = 0; j < 8; ++j) {
    int r = wr * 128 + j * 16 + rl;          // 0..255
    int r7 = r & 127;
    int lu = (r >> 7) * 4 + g;
    aoff[j] = r7 * 128 + ((lu ^ (r7 & 7)) << 4);
  }
#pragma unroll
  for (int i = 0; i < 4; ++i) {
    int r = wc * 64 + i * 16 + rl;           // 0..255
    int r7 = r & 127;
    int lu = (r >> 7) * 4 + g;
    boff[i] = 16384 + r7 * 128 + ((lu ^ (r7 & 7)) << 4);
  }

  // ---- staging: linear LDS dest + inverse-swizzled global source (rule #21) ----
  auto mkoff = [&](int sidx, int base0) -> size_t {
    int lrow = sidx >> 3, pu = sidx & 7;
    int lu = pu ^ (lrow & 7);
    int r = lrow + ((lu & 4) << 5);
    return (size_t)(base0 + r) * K + (lu & 3) * 8;
  };
  const u16* gA0 = Ae + mkoff(tid, m0);
  const u16* gA1 = Ae + mkoff(512 + tid, m0);
  const u16* gB0 = Be + mkoff(tid, n0);
  const u16* gB1 = Be + mkoff(512 + tid, n0);
  const int dA0 = tid * 16, dA1 = 8192 + tid * 16;
  const int dB0 = 16384 + tid * 16, dB1 = 24576 + tid * 16;

  f32x4 acc[8][4] = {};

  // ---- prologue: stage tiles 0,1,2 into bufs 0,1,2 ----
  auto prost = [&](auto SBC, int kb) {
    constexpr int SB = decltype(SBC)::value;
    char* sd = (char*)(((SB >= 2) ? smH : smL) + (SB & 1) * 32768);
    async_ld16((const char*)gA0 + kb, sd + dA0);
    async_ld16((const char*)gA1 + kb, sd + dA1);
    async_ld16((const char*)gB0 + kb, sd + dB0);
    async_ld16((const char*)gB1 + kb, sd + dB1);
  };
  prost(ic<0>{}, 0);
  prost(ic<1>{}, 64);
  prost(ic<2>{}, 128);
  asm volatile("s_waitcnt vmcnt(8)\n\ts_barrier" ::: "memory");

  // ---- one K-tile ----
  auto tileb = [&](auto JC, auto STC, auto WNC) {
    constexpr int J = decltype(JC)::value;
    constexpr bool ST = decltype(STC)::value;
    constexpr int WN = decltype(WNC)::value;
    constexpr int SB = (J + 3) & 3;
    constexpr int KOFF = (J + 3) * 64;   // bytes from current group base
    const char* sr = ((J >= 2) ? smH : smL) + (J & 1) * 32768;
    char* sd = (char*)(((SB >= 2) ? smH : smL) + (SB & 1) * 32768);
    if constexpr (ST) {
      async_ld16((const char*)gA0 + KOFF, sd + dA0);
      async_ld16((const char*)gA1 + KOFF, sd + dA1);
      async_ld16((const char*)gB0 + KOFF, sd + dB0);
      async_ld16((const char*)gB1 + KOFF, sd + dB1);
    }
    bf16x8 bfr[4], afr[8];
#pragma unroll
    for (int i = 0; i < 4; ++i) bfr[i] = *(const bf16x8*)(sr + boff[i]);
#pragma unroll
    for (int j = 0; j < 8; ++j) afr[j] = *(const bf16x8*)(sr + aoff[j]);
    // 12 ds_reads outstanding; wait to 4 -> bfr[0..3]+afr[0..3] resident
    asm volatile("s_waitcnt lgkmcnt(4)");
    __builtin_amdgcn_sched_barrier(0);
    __builtin_amdgcn_s_setprio(1);
#pragma unroll
    for (int j = 0; j < 4; ++j)
#pragma unroll
      for (int i = 0; i < 4; ++i)
        acc[j][i] = __builtin_amdgcn_mfma_f32_16x16x32_bf16(bfr[i], afr[j], acc[j][i], 0, 0, 0);
    asm volatile("s_waitcnt lgkmcnt(0)");
    __builtin_amdgcn_sched_barrier(0);
#pragma unroll
    for (int j = 4; j < 8; ++j)
#pragma unroll
      for (int i = 0; i < 4; ++i)
        acc[j][i] = __builtin_amdgcn_mfma_f32_16x16x32_bf16(bfr[i], afr[j], acc[j][i], 0, 0, 0);
    __builtin_amdgcn_s_setprio(0);
    if constexpr (WN >= 0) {
      asm volatile("s_waitcnt vmcnt(%0)\n\ts_barrier" :: "n"(WN) : "memory");
    }
  };

  // ---- main: groups of 4 tiles, steady state (stage t+3, wait vmcnt(8)) ----
#pragma unroll 1
  for (int gq = 0; gq < (NT - 4) / 4; ++gq) {
    tileb(ic<0>{}, std::true_type{}, ic<8>{});
    tileb(ic<1>{}, std::true_type{}, ic<8>{});
    tileb(ic<2>{}, std::true_type{}, ic<8>{});
    tileb(ic<3>{}, std::true_type{}, ic<8>{});
    gA0 += 128; gA1 += 128; gB0 += 128; gB1 += 128;   // 4 tiles * 32 elems
  }
  // ---- final group: tiles NT-4..NT-1 ----
  tileb(ic<0>{}, std::true_type{}, ic<8>{});    // stages NT-1
  tileb(ic<1>{}, std::false_type{}, ic<4>{});
  tileb(ic<2>{}, std::false_type{}, ic<0>{});
  tileb(ic<3>{}, std::false_type{}, ic<-1>{});

  // ---- epilogue (R3-verified mapping) ----
  const float* be = bias + (size_t)e * N;
  const int mb = m0 + wr * 128 + rl;
  const int nb = n0 + wc * 64 + g * 4;
  if constexpr (GELU_OUT) {
    u16* Oe = (u16*)Out + (size_t)e * (size_t)CAP * N;
#pragma unroll
    for (int j = 0; j < 8; ++j) {
      int m = mb + j * 16;
#pragma unroll
      for (int i = 0; i < 4; ++i) {
        int n = nb + i * 16;
        float4 bv = *(const float4*)(be + n);
        ushort4 o;
        o.x = f2bf(gelu_f(acc[j][i][0] + bv.x));
        o.y = f2bf(gelu_f(acc[j][i][1] + bv.y));
        o.z = f2bf(gelu_f(acc[j][i][2] + bv.z));
        o.w = f2bf(gelu_f(acc[j][i][3] + bv.w));
        *(ushort4*)(Oe + (size_t)m * N + n) = o;
      }
    }
  } else {
    float* Oe = (float*)Out + (size_t)e * (size_t)CAP * N;
#pragma unroll
    for (int j = 0; j < 8; ++j) {
      int m = mb + j * 16;
#pragma unroll
      for (int i = 0; i < 4; ++i) {
        int n = nb + i * 16;
        float4 bv = *(const float4*)(be + n);
        float4 o;
        o.x = acc[j][i][0] + bv.x;
        o.y = acc[j][i][1] + bv.y;
        o.z = acc[j][i][2] + bv.z;
        o.w = acc[j][i][3] + bv.w;
        *(float4*)(Oe + (size_t)m * N + n) = o;
      }
    }
  }
}

extern "C" void kernel_launch(void* const* d_in, const int* in_sizes, int n_in,
                              void* d_out, int out_size, void* d_ws, size_t ws_size,
                              hipStream_t stream) {
  const float* x  = (const float*)d_in[0];
  // d_in[1] = expert_size (equal splits by construction; unused)
  const float* w1 = (const float*)d_in[2];
  const float* b1 = (const float*)d_in[3];
  const float* w2 = (const float*)d_in[4];
  const float* b2 = (const float*)d_in[5];
  float* out = (float*)d_out;

  char* wsp = (char*)d_ws;
  u16* x_bf = (u16*)(wsp);                             // 64 MiB
  u16* w1t  = (u16*)(wsp + (size_t)67108864);          // 64 MiB  [E][DHID][DIN]
  u16* w2t  = (u16*)(wsp + (size_t)134217728);         // 64 MiB  [E][DOUT][DHID]
  u16* h    = (u16*)(wsp + (size_t)201326592);         // 256 MiB [NTOK][DHID]

  hipFuncSetAttribute(reinterpret_cast<const void*>(moe_gemm256_kernel<DIN, DHID, true>),
                      hipFuncAttributeMaxDynamicSharedMemorySize, 131072);
  hipFuncSetAttribute(reinterpret_cast<const void*>(moe_gemm256_kernel<DHID, DOUTD, false>),
                      hipFuncAttributeMaxDynamicSharedMemorySize, 131072);

  convert_bf16_kernel<<<(NTOK * DIN) / (256 * 8), 256, 0, stream>>>(x, x_bf);
  transpose_bf16_kernel<<<dim3(DHID / 64, DIN / 64, NE), 256, 0, stream>>>(w1, w1t, DIN, DHID);
  transpose_bf16_kernel<<<dim3(DOUTD / 64, DHID / 64, NE), 256, 0, stream>>>(w2, w2t, DHID, DOUTD);

  moe_gemm256_kernel<DIN, DHID, true>
      <<<dim3(NE * (CAP / 256) * (DHID / 256)), 512, 131072, stream>>>(x_bf, w1t, b1, h);
  moe_gemm256_kernel<DHID, DOUTD, false>
      <<<dim3(NE * (CAP / 256) * (DOUTD / 256)), 512, 131072, stream>>>(h, w2t, b2, out);
}

// Round 6
// 716.536 us; speedup vs baseline: 1.1135x; 1.0315x over previous
//
#include <hip/hip_runtime.h>
#include <hip/hip_bf16.h>
#include <type_traits>

#define NE 8
#define DIN 1024
#define DHID 4096
#define DOUTD 1024
#define NTOK 32768
#define CAP (NTOK / NE)  // 4096 tokens per expert

typedef unsigned short u16;
typedef __attribute__((ext_vector_type(8))) short bf16x8;   // 8 bf16 = 4 VGPR
typedef __attribute__((ext_vector_type(4))) float f32x4;

template <int I> using ic = std::integral_constant<int, I>;

__device__ __forceinline__ u16 f2bf(float x) {
  unsigned u = __builtin_bit_cast(unsigned, x);
  u += 0x7fffu + ((u >> 16) & 1u);   // RNE; finite normals
  return (u16)(u >> 16);
}

// tanh-form GELU (max dev from erf-form ~3e-4; threshold headroom ~4.6x; R4/R5-verified)
__device__ __forceinline__ float gelu_f(float x) {
  float u = 0.7978845608028654f * x * (1.0f + 0.044715f * x * x);
  float t = __expf(-2.0f * fabsf(u));
  float r = __fdividef(2.0f * t, 1.0f + t);   // 1 - tanh|u|
  float th = copysignf(1.0f - r, u);
  return 0.5f * x * (1.0f + th);
}

__device__ __forceinline__ void async_ld16(const void* g, void* l) {
  __builtin_amdgcn_global_load_lds(
      (const __attribute__((address_space(1))) unsigned int*)g,
      (__attribute__((address_space(3))) unsigned int*)l, 16, 0, 0);
}

// ---------------- fp32 -> bf16, 8 elems/thread ----------------
__global__ __launch_bounds__(256) void convert_bf16_kernel(const float* __restrict__ in,
                                                           u16* __restrict__ out) {
  size_t i = ((size_t)blockIdx.x * 256 + threadIdx.x) * 8;
  float4 a = *(const float4*)(in + i);
  float4 b = *(const float4*)(in + i + 4);
  uint4 o;
  o.x = (unsigned)f2bf(a.x) | ((unsigned)f2bf(a.y) << 16);
  o.y = (unsigned)f2bf(a.z) | ((unsigned)f2bf(a.w) << 16);
  o.z = (unsigned)f2bf(b.x) | ((unsigned)f2bf(b.y) << 16);
  o.w = (unsigned)f2bf(b.z) | ((unsigned)f2bf(b.w) << 16);
  *(uint4*)(out + i) = o;
}

// ------------- [E][K][N] fp32 -> [E][N][K] bf16 (64x64 LDS-tiled) -------------
__global__ __launch_bounds__(256) void transpose_bf16_kernel(const float* __restrict__ in,
                                                             u16* __restrict__ out,
                                                             int K, int N) {
  __shared__ __align__(16) u16 tile[64 * 72];
  const int e = blockIdx.z;
  const int n0 = blockIdx.x * 64;
  const int k0 = blockIdx.y * 64;
  const float* inp = in + (size_t)e * K * N;
  u16* outp = out + (size_t)e * N * K;
  const int t = threadIdx.x;
  const int kr = t >> 4;
  const int nc = (t & 15) * 4;
#pragma unroll
  for (int rr = 0; rr < 4; ++rr) {
    int kl = rr * 16 + kr;
    float4 v = *(const float4*)(inp + (size_t)(k0 + kl) * N + n0 + nc);
    tile[(nc + 0) * 72 + kl] = f2bf(v.x);
    tile[(nc + 1) * 72 + kl] = f2bf(v.y);
    tile[(nc + 2) * 72 + kl] = f2bf(v.z);
    tile[(nc + 3) * 72 + kl] = f2bf(v.w);
  }
  __syncthreads();
  const int nr = t >> 3;
  const int kc = (t & 7) * 8;
#pragma unroll
  for (int it = 0; it < 2; ++it) {
    int nl = it * 32 + nr;
    bf16x8 w = *(const bf16x8*)(tile + nl * 72 + kc);
    *(bf16x8*)(outp + (size_t)(n0 + nl) * K + k0 + kc) = w;
  }
}

// ------ grouped GEMM, 256x256, ring-4, barrier-BEFORE-MFMA (cross-tile overlap) ------
// C[e] = A[e] (CAP x K bf16 row-major) @ Bt[e]^T (Bt: N x K bf16 row-major).
// 8 waves (2M x 4N), per-wave 128x64, MFMA 16x16x32 (acc f32x4[8][4]).
// BK=32, ring-4 LDS (4 x 32KiB = 128 KiB), K-loop unrolled by 4 => all LDS addrs
// are base + constexpr immediate. Prefetch depth 3 (stage t+3 at t).
// Per tile (NEW vs R5 — gate moved BEFORE the MFMA cluster):
//   {4x global_load_lds(t+3) | 12x ds_read(buf t) | lgkmcnt(0) [mem-clobber] |
//    fused vmcnt(WN)+s_barrier | sched_barrier(0) | setprio(1) 32 MFMA setprio(0)}
// => MFMA(t) and [stage+ds_read](t+1) share one scheduling region with NO barrier
// between them: compiler ILP + 2-wave TLP hide LDS latency & barrier under MFMA.
// Safety: lgkmcnt(0) has "memory" clobber so ds_reads cannot sink past it — all
// reads of buf[t] retire before the barrier; stage into buf[t] (=buf[(t+4)&3])
// happens at iter t+1, after that barrier. sched_barrier(0) after the barrier
// stops MFMA hoisting above the waits (rule #18).
// vmcnt ledger (4 loads/tile/thread): at iter t's gate, outstanding = t+1,t+2,t+3
// = 12; wait vmcnt(8) retires t+1 (read next iter). Tail: 8,4,0,none. Never
// drains in steady state (T4). Prologue: stage 0,1,2; vmcnt(8)+barrier.
// LDS tile layout (R1-R5, measured 0 conflicts): region [128 lds-rows][8 x 16B units];
// global (r,k): lds_row=r&127, lu=(r>>7)*4+(k>>3), phys unit=lu^(lds_row&7) (T2);
// staged via linear LDS dest + inverse-swizzled global source (rule #21).
// L2 supertiling: 4x4 tile supertiles per expert => per-XCD working set
// 4 A-panels + 4 B-panels = 4 MB (fits 4 MB XCD L2); was 16 MB (thrash).
// MFMA swapped (Aop=weights bfr, Bop=tokens afr); C/D per R3 (verified):
//   acc[j][i] lane l reg r -> C[m0+wr*128+j*16+(l&15)][n0+wc*64+i*16+(l>>4)*4+r]
template <int K, int N, bool GELU_OUT>
__global__ __launch_bounds__(512, 2) void moe_gemm256_kernel(
    const u16* __restrict__ A, const u16* __restrict__ Bt,
    const float* __restrict__ bias, void* __restrict__ Out) {
  extern __shared__ __align__(16) char smem_raw[];
  constexpr int TX = N / 256;
  constexpr int NT = K / 32;
  static_assert(NT % 4 == 0 && NT >= 8, "K-tile count");
  static_assert(TX == 4 || TX == 16, "supertile map assumes TX in {4,16}");

  const int bid = blockIdx.x;
  const int e = bid & 7;          // XCD swizzle: nwg%8==0, one expert per XCD
  const int idx = bid >> 3;
  // 4x4 supertiles over the (MT=16) x TX tile grid (L2 working-set fit)
  constexpr int STC = TX / 4;     // supertile cols
  const int st = idx >> 4;        // supertile id
  const int win = idx & 15;       // position within supertile
  const int m0 = ((st / STC) * 4 + (win >> 2)) * 256;
  const int n0 = ((st % STC) * 4 + (win & 3)) * 256;

  const u16* Ae = A + (size_t)e * CAP * K;
  const u16* Be = Bt + (size_t)e * N * K;

  const int tid = threadIdx.x;
  const int l = tid & 63;
  const int w = tid >> 6;
  const int wr = w >> 2;          // 0..1 (M)
  const int wc = w & 3;           // 0..3 (N)
  const int g = l >> 4;           // 0..3 (k-unit)
  const int rl = l & 15;

  const char* smL = smem_raw;
  const char* smH = smem_raw + 65536;

  // ---- ds_read byte offsets within a buffer (swizzled, loop-invariant) ----
  int aoff[8], boff[4];
#pragma unroll
  for (int j = 0; j < 8; ++j) {
    int r = wr * 128 + j * 16 + rl;          // 0..255
    int r7 = r & 127;
    int lu = (r >> 7) * 4 + g;
    aoff[j] = r7 * 128 + ((lu ^ (r7 & 7)) << 4);
  }
#pragma unroll
  for (int i = 0; i < 4; ++i) {
    int r = wc * 64 + i * 16 + rl;           // 0..255
    int r7 = r & 127;
    int lu = (r >> 7) * 4 + g;
    boff[i] = 16384 + r7 * 128 + ((lu ^ (r7 & 7)) << 4);
  }

  // ---- staging: linear LDS dest + inverse-swizzled global source (rule #21) ----
  auto mkoff = [&](int sidx, int base0) -> size_t {
    int lrow = sidx >> 3, pu = sidx & 7;
    int lu = pu ^ (lrow & 7);
    int r = lrow + ((lu & 4) << 5);
    return (size_t)(base0 + r) * K + (lu & 3) * 8;
  };
  const u16* gA0 = Ae + mkoff(tid, m0);
  const u16* gA1 = Ae + mkoff(512 + tid, m0);
  const u16* gB0 = Be + mkoff(tid, n0);
  const u16* gB1 = Be + mkoff(512 + tid, n0);
  const int dA0 = tid * 16, dA1 = 8192 + tid * 16;
  const int dB0 = 16384 + tid * 16, dB1 = 24576 + tid * 16;

  f32x4 acc[8][4] = {};

  // ---- prologue: stage tiles 0,1,2 into bufs 0,1,2; gate tile 0 ----
  auto prost = [&](auto SBC, int kb) {
    constexpr int SB = decltype(SBC)::value;
    char* sd = (char*)(((SB >= 2) ? smH : smL) + (SB & 1) * 32768);
    async_ld16((const char*)gA0 + kb, sd + dA0);
    async_ld16((const char*)gA1 + kb, sd + dA1);
    async_ld16((const char*)gB0 + kb, sd + dB0);
    async_ld16((const char*)gB1 + kb, sd + dB1);
  };
  prost(ic<0>{}, 0);
  prost(ic<1>{}, 64);
  prost(ic<2>{}, 128);
  asm volatile("s_waitcnt vmcnt(8)\n\ts_barrier" ::: "memory");
  __builtin_amdgcn_sched_barrier(0);

  // ---- one K-tile ----
  auto tileb = [&](auto JC, auto STC_, auto WNC) {
    constexpr int J = decltype(JC)::value;
    constexpr bool ST = decltype(STC_)::value;
    constexpr int WN = decltype(WNC)::value;
    constexpr int SB = (J + 3) & 3;
    constexpr int KOFF = (J + 3) * 64;   // bytes from current group base
    const char* sr = ((J >= 2) ? smH : smL) + (J & 1) * 32768;
    char* sd = (char*)(((SB >= 2) ? smH : smL) + (SB & 1) * 32768);
    if constexpr (ST) {
      async_ld16((const char*)gA0 + KOFF, sd + dA0);
      async_ld16((const char*)gA1 + KOFF, sd + dA1);
      async_ld16((const char*)gB0 + KOFF, sd + dB0);
      async_ld16((const char*)gB1 + KOFF, sd + dB1);
    }
    bf16x8 bfr[4], afr[8];
#pragma unroll
    for (int i = 0; i < 4; ++i) bfr[i] = *(const bf16x8*)(sr + boff[i]);
#pragma unroll
    for (int j = 0; j < 8; ++j) afr[j] = *(const bf16x8*)(sr + aoff[j]);
    // all reads of buf[J] must retire BEFORE the barrier (WAR vs restage at t+1):
    asm volatile("s_waitcnt lgkmcnt(0)" ::: "memory");
    if constexpr (WN >= 0) {
      asm volatile("s_waitcnt vmcnt(%0)\n\ts_barrier" :: "n"(WN) : "memory");
    }
    __builtin_amdgcn_sched_barrier(0);   // rule #18: MFMA must not hoist above waits
    __builtin_amdgcn_s_setprio(1);
#pragma unroll
    for (int j = 0; j < 4; ++j)
#pragma unroll
      for (int i = 0; i < 4; ++i)
        acc[j][i] = __builtin_amdgcn_mfma_f32_16x16x32_bf16(bfr[i], afr[j], acc[j][i], 0, 0, 0);
#pragma unroll
    for (int j = 4; j < 8; ++j)
#pragma unroll
      for (int i = 0; i < 4; ++i)
        acc[j][i] = __builtin_amdgcn_mfma_f32_16x16x32_bf16(bfr[i], afr[j], acc[j][i], 0, 0, 0);
    __builtin_amdgcn_s_setprio(0);
  };

  // ---- main: groups of 4 tiles, steady state (stage t+3, gate vmcnt(8)) ----
#pragma unroll 1
  for (int gq = 0; gq < (NT - 4) / 4; ++gq) {
    tileb(ic<0>{}, std::true_type{}, ic<8>{});
    tileb(ic<1>{}, std::true_type{}, ic<8>{});
    tileb(ic<2>{}, std::true_type{}, ic<8>{});
    tileb(ic<3>{}, std::true_type{}, ic<8>{});
    gA0 += 128; gA1 += 128; gB0 += 128; gB1 += 128;   // 4 tiles * 32 elems
  }
  // ---- final group: tiles NT-4..NT-1 ----
  tileb(ic<0>{}, std::true_type{}, ic<8>{});    // stages NT-1; gate retires NT-3
  tileb(ic<1>{}, std::false_type{}, ic<4>{});   // gate retires NT-2
  tileb(ic<2>{}, std::false_type{}, ic<0>{});   // gate retires NT-1
  tileb(ic<3>{}, std::false_type{}, ic<-1>{});  // no gate; lgkm0 covers own reads

  // ---- epilogue (R3-verified mapping) ----
  const float* be = bias + (size_t)e * N;
  const int mb = m0 + wr * 128 + rl;
  const int nb = n0 + wc * 64 + g * 4;
  if constexpr (GELU_OUT) {
    u16* Oe = (u16*)Out + (size_t)e * (size_t)CAP * N;
#pragma unroll
    for (int j = 0; j < 8; ++j) {
      int m = mb + j * 16;
#pragma unroll
      for (int i = 0; i < 4; ++i) {
        int n = nb + i * 16;
        float4 bv = *(const float4*)(be + n);
        ushort4 o;
        o.x = f2bf(gelu_f(acc[j][i][0] + bv.x));
        o.y = f2bf(gelu_f(acc[j][i][1] + bv.y));
        o.z = f2bf(gelu_f(acc[j][i][2] + bv.z));
        o.w = f2bf(gelu_f(acc[j][i][3] + bv.w));
        *(ushort4*)(Oe + (size_t)m * N + n) = o;
      }
    }
  } else {
    float* Oe = (float*)Out + (size_t)e * (size_t)CAP * N;
#pragma unroll
    for (int j = 0; j < 8; ++j) {
      int m = mb + j * 16;
#pragma unroll
      for (int i = 0; i < 4; ++i) {
        int n = nb + i * 16;
        float4 bv = *(const float4*)(be + n);
        float4 o;
        o.x = acc[j][i][0] + bv.x;
        o.y = acc[j][i][1] + bv.y;
        o.z = acc[j][i][2] + bv.z;
        o.w = acc[j][i][3] + bv.w;
        *(float4*)(Oe + (size_t)m * N + n) = o;
      }
    }
  }
}

extern "C" void kernel_launch(void* const* d_in, const int* in_sizes, int n_in,
                              void* d_out, int out_size, void* d_ws, size_t ws_size,
                              hipStream_t stream) {
  const float* x  = (const float*)d_in[0];
  // d_in[1] = expert_size (equal splits by construction; unused)
  const float* w1 = (const float*)d_in[2];
  const float* b1 = (const float*)d_in[3];
  const float* w2 = (const float*)d_in[4];
  const float* b2 = (const float*)d_in[5];
  float* out = (float*)d_out;

  char* wsp = (char*)d_ws;
  u16* x_bf = (u16*)(wsp);                             // 64 MiB
  u16* w1t  = (u16*)(wsp + (size_t)67108864);          // 64 MiB  [E][DHID][DIN]
  u16* w2t  = (u16*)(wsp + (size_t)134217728);         // 64 MiB  [E][DOUT][DHID]
  u16* h    = (u16*)(wsp + (size_t)201326592);         // 256 MiB [NTOK][DHID]

  hipFuncSetAttribute(reinterpret_cast<const void*>(moe_gemm256_kernel<DIN, DHID, true>),
                      hipFuncAttributeMaxDynamicSharedMemorySize, 131072);
  hipFuncSetAttribute(reinterpret_cast<const void*>(moe_gemm256_kernel<DHID, DOUTD, false>),
                      hipFuncAttributeMaxDynamicSharedMemorySize, 131072);

  convert_bf16_kernel<<<(NTOK * DIN) / (256 * 8), 256, 0, stream>>>(x, x_bf);
  transpose_bf16_kernel<<<dim3(DHID / 64, DIN / 64, NE), 256, 0, stream>>>(w1, w1t, DIN, DHID);
  transpose_bf16_kernel<<<dim3(DOUTD / 64, DHID / 64, NE), 256, 0, stream>>>(w2, w2t, DHID, DOUTD);

  moe_gemm256_kernel<DIN, DHID, true>
      <<<dim3(NE * (CAP / 256) * (DHID / 256)), 512, 131072, stream>>>(x_bf, w1t, b1, h);
  moe_gemm256_kernel<DHID, DOUTD, false>
      <<<dim3(NE * (CAP / 256) * (DOUTD / 256)), 512, 131072, stream>>>(h, w2t, b2, out);
}